// Round 2
// baseline (1646.716 us; speedup 1.0000x reference)
//
#include <hip/hip_runtime.h>

// ---------------- types / helpers ----------------
typedef __bf16 bf16x8 __attribute__((ext_vector_type(8)));
typedef float f32x4 __attribute__((ext_vector_type(4)));
typedef unsigned short u16x8 __attribute__((ext_vector_type(8)));

__device__ __forceinline__ unsigned short f2bf(float f) {
  union { float f; unsigned int u; } v; v.f = f;
  unsigned int r = v.u + 0x7fffu + ((v.u >> 16) & 1u);  // RNE
  return (unsigned short)(r >> 16);
}

__device__ __forceinline__ void async16(const unsigned short* g, unsigned short* l) {
  __builtin_amdgcn_global_load_lds(
      (const __attribute__((address_space(1))) unsigned int*)g,
      (__attribute__((address_space(3))) unsigned int*)l, 16, 0, 0);
}

// ---------------- fused converts: all weights + memory + bias concat, ONE launch ------
__global__ void cvt_all(const float* __restrict__ q_w, const float* __restrict__ k_w,
                        const float* __restrict__ v_w, const float* __restrict__ o_w,
                        const float* __restrict__ f1w, const float* __restrict__ f2w,
                        const float* __restrict__ mem,
                        const float* __restrict__ q_b, const float* __restrict__ k_b,
                        const float* __restrict__ v_b,
                        unsigned short* __restrict__ WQ, unsigned short* __restrict__ WK,
                        unsigned short* __restrict__ WV, unsigned short* __restrict__ WO,
                        unsigned short* __restrict__ WF1, unsigned short* __restrict__ WF2,
                        unsigned short* __restrict__ MEMB, float* __restrict__ QKVB) {
  const int bid = blockIdx.x;
  const float* src; unsigned short* dst; float scale = 1.f; int base;
  if (bid < 1024)       { src = q_w; dst = WQ;  scale = 0.125f; base = 0; }
  else if (bid < 2048)  { src = k_w; dst = WK;  base = 1024; }
  else if (bid < 3072)  { src = v_w; dst = WV;  base = 2048; }
  else if (bid < 4096)  { src = o_w; dst = WO;  base = 3072; }
  else if (bid < 8192)  { src = f1w; dst = WF1; base = 4096; }
  else if (bid < 12288) { src = f2w; dst = WF2; base = 8192; }
  else if (bid < 13312) { src = mem; dst = MEMB; base = 12288; }
  else {  // bias concat (12 blocks, 3072 elems), q-bias pre-scaled
    const int i = (bid - 13312) * 256 + threadIdx.x;
    QKVB[i] = (i < 1024) ? q_b[i] * 0.125f : (i < 2048 ? k_b[i - 1024] : v_b[i - 2048]);
    return;
  }
  const int i = (bid - base) * 256 + threadIdx.x;
  float4 v = ((const float4*)src)[i];
  ushort4 o;
  o.x = f2bf(v.x * scale); o.y = f2bf(v.y * scale);
  o.z = f2bf(v.z * scale); o.w = f2bf(v.w * scale);
  ((ushort4*)dst)[i] = o;
}

// ---------------- LayerNorm (per 1024-row) -> bf16 ----------------
template <int PREFILL>
__global__ __launch_bounds__(256) void ln_bf16(
    const float* __restrict__ src, unsigned short* __restrict__ dst,
    const float* __restrict__ g, const float* __restrict__ be,
    const float* __restrict__ fbias, float* __restrict__ dout) {
  const int row = blockIdx.x, tid = threadIdx.x;
  const float4 v = ((const float4*)(src + (size_t)row * 1024))[tid];
  if (PREFILL) {
    const float4 fb = ((const float4*)fbias)[tid];
    float4 r;
    r.x = v.x + fb.x; r.y = v.y + fb.y; r.z = v.z + fb.z; r.w = v.w + fb.w;
    ((float4*)(dout + (size_t)row * 1024))[tid] = r;
  }
  float s = v.x + v.y + v.z + v.w;
  float qq = v.x * v.x + v.y * v.y + v.z * v.z + v.w * v.w;
#pragma unroll
  for (int off = 32; off; off >>= 1) { s += __shfl_xor(s, off); qq += __shfl_xor(qq, off); }
  __shared__ float ps[4], pq[4];
  const int w = tid >> 6, lane = tid & 63;
  if (lane == 0) { ps[w] = s; pq[w] = qq; }
  __syncthreads();
  if (tid == 0) { ps[0] = ps[0] + ps[1] + ps[2] + ps[3]; pq[0] = pq[0] + pq[1] + pq[2] + pq[3]; }
  __syncthreads();
  const float mu = ps[0] * (1.f / 1024.f);
  const float var = pq[0] * (1.f / 1024.f) - mu * mu;
  const float rs = rsqrtf(var + 1e-5f);
  const float4 gv = ((const float4*)g)[tid];
  const float4 bv = ((const float4*)be)[tid];
  ushort4 o;
  o.x = f2bf((v.x - mu) * rs * gv.x + bv.x);
  o.y = f2bf((v.y - mu) * rs * gv.y + bv.y);
  o.z = f2bf((v.z - mu) * rs * gv.z + bv.z);
  o.w = f2bf((v.w - mu) * rs * gv.w + bv.w);
  ((ushort4*)(dst + (size_t)row * 1024))[tid] = o;
}

// ---------------- GEMM: C[M,N] = A[M,K] @ B[N,K]^T (+ bias), m97-style ----------------
// __launch_bounds__(256, 8): pin VGPR<=64 (round-0 codegen compiled at 64 naturally;
// round-1 co-compilation perturbed it to 80 and cost ~11 us on QKV — rule #19).
#define KOFF 6291456ull
#define VOFF 13631488ull
template <int EPI>
__global__ __launch_bounds__(256, 8) void gemm_bt(
    const unsigned short* __restrict__ A, const unsigned short* __restrict__ Bw,
    const float* __restrict__ bias, const float* __restrict__ resid,
    void* __restrict__ Cout, int M, int N, int K, int lda, int ldb, int NBN, int WM) {
  __shared__ __align__(16) unsigned short lA[128 * 32];
  __shared__ __align__(16) unsigned short lB[128 * 32];
  const int tid = threadIdx.x;
  const int w = tid >> 6, lane = tid & 63;
  const int lr = lane & 15, lq = lane >> 4;
  const int l = blockIdx.x;
  const int xcd = l & 7, r = l >> 3;
  const int bm = xcd * WM + (r % WM);
  const int rest = r / WM;
  const int bn = rest % NBN;
  const size_t koff = (size_t)(rest / NBN) * K;  // split-K offset
  const unsigned short* Ab = A + (size_t)bm * 128 * lda + koff;
  const unsigned short* Bb = Bw + (size_t)bn * 128 * ldb + koff;
  const int wm = (w & 1) << 6, wn = (w >> 1) << 6;
  f32x4 acc[4][4] = {};
  const int kiters = K >> 5;
  const int c0 = tid, c1 = 256 + tid;
  const int r0 = c0 >> 2, o0 = (c0 & 3) << 3;
  const int r1 = c1 >> 2, o1 = (c1 & 3) << 3;
  for (int kt = 0; kt < kiters; ++kt) {
    const int kb = kt << 5;
    __syncthreads();
    async16(Ab + (size_t)r0 * lda + kb + o0, lA + c0 * 8);
    async16(Bb + (size_t)r0 * ldb + kb + o0, lB + c0 * 8);
    async16(Ab + (size_t)r1 * lda + kb + o1, lA + c1 * 8);
    async16(Bb + (size_t)r1 * ldb + kb + o1, lB + c1 * 8);
    __syncthreads();
    bf16x8 af[4], bfr[4];
#pragma unroll
    for (int i = 0; i < 4; ++i) af[i] = *(const bf16x8*)(lA + (wm + i * 16 + lr) * 32 + lq * 8);
#pragma unroll
    for (int i = 0; i < 4; ++i) bfr[i] = *(const bf16x8*)(lB + (wn + i * 16 + lr) * 32 + lq * 8);
#pragma unroll
    for (int i = 0; i < 4; ++i)
#pragma unroll
      for (int j = 0; j < 4; ++j)
        acc[i][j] = __builtin_amdgcn_mfma_f32_16x16x32_bf16(af[i], bfr[j], acc[i][j], 0, 0, 0);
  }
  const int which = (bn * 128) >> 10;  // EPI5: 0=Q,1=K,2=V (block-uniform; 1024%128==0)
#pragma unroll
  for (int i = 0; i < 4; ++i) {
#pragma unroll
    for (int j = 0; j < 4; ++j) {
      const int colg = bn * 128 + wn + j * 16 + lr;
      const float bi = (EPI == 6) ? 0.f : bias[colg];
      const int rowg0 = bm * 128 + wm + i * 16 + lq * 4;
#pragma unroll
      for (int r2 = 0; r2 < 4; ++r2) {
        const int rowg = rowg0 + r2;
        const float val = acc[i][j][r2] + bi;
        if (EPI == 5) {
          const int t = rowg >> 4, bb = rowg & 15;
          const int hh = (colg >> 6) & 15, dd = colg & 63;
          const size_t nn = (size_t)(bb * 16 + hh);
          unsigned short* q16 = (unsigned short*)Cout;
          if (which == 0) {
            if (rowg >= 1024) q16[(nn * 384 + (t - 64)) * 64 + dd] = f2bf(val);
          } else if (which == 1) {
            q16[KOFF + (nn * 448 + t) * 64 + dd] = f2bf(val);
          } else {
            q16[VOFF + (nn * 448 + t) * 64 + dd] = f2bf(val);
          }
        } else {
          const size_t idx = (size_t)rowg * N + colg;
          if (EPI == 2) ((float*)Cout)[idx] = val + resid[idx];
          else if (EPI == 3) ((unsigned short*)Cout)[idx] = f2bf(fmaxf(val, 0.f));
          else if (EPI == 6) atomicAdd(&((float*)Cout)[idx], acc[i][j][r2]);
        }
      }
    }
  }
}

// ---------------- 2-phase/kt 256x128 GEMM engine (counted vmcnt + setprio) ----------
// C = relu(A[M,K]@B[N,K]^T + bias) -> bf16. K=1024 fixed (16 k-tiles of BK=64).
// BM=256, BN=128 -> fc1 grid = 24*32 = 768 = EXACTLY 3 blocks/CU rounds (round-1's
// 384-block 256x256 config ran 2 rounds at 75% tail efficiency — the gain vanished).
// 512 thr = 8 waves (4M x 2N), per-wave 64x64 output (acc 4x4 f32x4 = 64 VGPR).
// LDS 96 KiB: A [2 buf][2 ks][256][32], B [2 buf][2 ks][128][32].
// Phase (2 per kt): head {lgkmcnt(0); vmcnt(6) counted; s_barrier} ; stage one
// (A-ks,B-ks) pair of kt+2 (3 loads/thread); ds_read next phase's frags; setprio(1);
// 16 MFMA; setprio(0). In-flight ledger: 3 loads/phase, 2 kt ahead -> at every
// steady head the oldest-6 drain is exactly the region read this phase. Tail
// (kt>=14) drains vmcnt 0 so nothing is in flight at endpgm.
#define WAITV6()  asm volatile("s_waitcnt vmcnt(6)" ::: "memory")
#define WAITV0()  asm volatile("s_waitcnt vmcnt(0)" ::: "memory")
#define WAITL0()  asm volatile("s_waitcnt lgkmcnt(0)" ::: "memory")
#define BAR()     do { __builtin_amdgcn_s_barrier(); __builtin_amdgcn_sched_barrier(0); } while (0)
#define SCHED()   __builtin_amdgcn_sched_barrier(0)

#define STG_A(bufv, ksv, ktv) do { \
    unsigned short* d_ = (unsigned short*)lA8 + (bufv) * 16384 + (ksv) * 8192; \
    const unsigned short* s_ = Ab + (((ktv) << 6) + ((ksv) << 5)); \
    async16(s_ + (size_t)ar0 * lda + ac0, d_ + ci0 * 8); \
    async16(s_ + (size_t)ar1 * lda + ac1, d_ + ci1 * 8); } while (0)
#define STG_B(bufv, ksv, ktv) do { \
    unsigned short* d_ = (unsigned short*)lB8 + (bufv) * 8192 + (ksv) * 4096; \
    const unsigned short* s_ = Bb + (((ktv) << 6) + ((ksv) << 5)); \
    async16(s_ + (size_t)br0 * ldb + bc0, d_ + tid * 8); } while (0)
#define RD_A4(dst, bufv, ksv) \
  _Pragma("unroll") \
  for (int i = 0; i < 4; ++i) \
    dst[i] = *(const bf16x8*)((unsigned short*)lA8 + (bufv) * 16384 + (ksv) * 8192 + \
                              (wm * 64 + i * 16 + lr) * 32 + lq * 8)
#define RD_B4(dst, bufv, ksv) \
  _Pragma("unroll") \
  for (int j = 0; j < 4; ++j) \
    dst[j] = *(const bf16x8*)((unsigned short*)lB8 + (bufv) * 8192 + (ksv) * 4096 + \
                              (wn * 64 + j * 16 + lr) * 32 + lq * 8)
#define MFMA16(av, bv) \
  _Pragma("unroll") \
  for (int i = 0; i < 4; ++i) \
  _Pragma("unroll") \
  for (int j = 0; j < 4; ++j) \
    acc[i][j] = \
        __builtin_amdgcn_mfma_f32_16x16x32_bf16(av[i], bv[j], acc[i][j], 0, 0, 0)

__global__ __launch_bounds__(512, 2) void gemm8_relu(
    const unsigned short* __restrict__ A, const unsigned short* __restrict__ Bw,
    const float* __restrict__ bias, unsigned short* __restrict__ Cout,
    int N, int lda, int ldb, int MT) {  // grid must be 8 * MT * (N/128)
  __shared__ __align__(16) unsigned short lA8[32768];  // [2][2][256][32] u16 = 64 KiB
  __shared__ __align__(16) unsigned short lB8[16384];  // [2][2][128][32] u16 = 32 KiB
  const int tid = threadIdx.x;
  const int w = tid >> 6, lane = tid & 63;
  const int wm = w >> 1, wn = w & 1;          // wave grid 4 (M) x 2 (N)
  const int lr = lane & 15, lq = lane >> 4;
  const int bid = blockIdx.x;
  const int xcd = bid & 7, r = bid >> 3;
  const int bm = xcd * MT + (r % MT);         // per-XCD contiguous A stripe (L2 reuse)
  const int bn = r / MT;
  const unsigned short* Ab = A + (size_t)bm * 256 * lda;
  const unsigned short* Bb = Bw + (size_t)bn * 128 * ldb;
  // staging: A region = 16KB = 1024 chunks (thread owns tid, tid+512);
  //          B region =  8KB =  512 chunks (thread owns tid). LDS dest linear in chunk.
  const int ci0 = tid, ci1 = tid + 512;
  const int ar0 = ci0 >> 2, ac0 = (ci0 & 3) << 3;
  const int ar1 = ci1 >> 2, ac1 = (ci1 & 3) << 3;
  const int br0 = tid >> 2, bc0 = (tid & 3) << 3;

  f32x4 acc[4][4] = {};
  bf16x8 aP[4], aN[4], b0[4], b1[4];

  // prologue: stage kt0 -> buf0, kt1 -> buf1 (6 loads each)
  STG_B(0, 0, 0); STG_A(0, 0, 0); STG_B(0, 1, 0); STG_A(0, 1, 0);
  STG_B(1, 0, 1); STG_A(1, 0, 1); STG_B(1, 1, 1); STG_A(1, 1, 1);
  WAITV6();   // kt0's 6 landed; kt1's 6 stay in flight
  BAR();
  RD_A4(aP, 0, 0);
  RD_B4(b0, 0, 0);

  for (int kt = 0; kt < 16; ++kt) {
    const int buf = kt & 1, nbuf = buf ^ 1, kt2 = kt + 2;
    const bool st = kt2 < 16, tail = kt >= 14;
    // ---- phase 0: MFMA ks0 ; stage (B,A)-ks0 of kt+2 ; read ks1 frags of kt
    WAITL0(); if (tail) { WAITV0(); } else { WAITV6(); } BAR();
    if (st) { STG_B(buf, 0, kt2); STG_A(buf, 0, kt2); }
    RD_A4(aN, buf, 1);
    RD_B4(b1, buf, 1);
    SCHED();
    __builtin_amdgcn_s_setprio(1);
    MFMA16(aP, b0);
    __builtin_amdgcn_s_setprio(0);
    // ---- phase 1: MFMA ks1 ; stage (B,A)-ks1 of kt+2 ; read ks0 frags of kt+1
    WAITL0(); if (tail) { WAITV0(); } else { WAITV6(); } BAR();
    if (st) { STG_B(buf, 1, kt2); STG_A(buf, 1, kt2); }
    if (kt < 15) { RD_A4(aP, nbuf, 0); RD_B4(b0, nbuf, 0); }
    SCHED();
    __builtin_amdgcn_s_setprio(1);
    MFMA16(aN, b1);
    __builtin_amdgcn_s_setprio(0);
  }

  // epilogue: relu(acc + bias) -> bf16 (same lane->(row,col) mapping as gemm_bt, proven)
#pragma unroll
  for (int j = 0; j < 4; ++j) {
    const int colg = bn * 128 + wn * 64 + j * 16 + lr;
    const float bi = bias[colg];
#pragma unroll
    for (int i = 0; i < 4; ++i) {
      const int rowg0 = bm * 256 + wm * 64 + i * 16 + lq * 4;
#pragma unroll
      for (int r2 = 0; r2 < 4; ++r2) {
        const float v = acc[i][j][r2] + bi;
        Cout[(size_t)(rowg0 + r2) * N + colg] = f2bf(fmaxf(v, 0.f));
      }
    }
  }
}

// ---------------- V transpose: vb[n][t][d] -> vt[n][d][t] ----------------
__global__ __launch_bounds__(256) void vtrans(const unsigned short* __restrict__ vb,
                                              unsigned short* __restrict__ vt) {
  __shared__ __align__(16) unsigned short ls[64][80];
  const int kc = blockIdx.x, n = blockIdx.y;
  const int tid = threadIdx.x;
#pragma unroll
  for (int i = 0; i < 2; ++i) {
    const int c = i * 256 + tid;
    const int kk = c >> 3, dc = (c & 7) << 3;
    u16x8 val = *(const u16x8*)(vb + ((size_t)n * 448 + kc * 64 + kk) * 64 + dc);
    *(u16x8*)&ls[kk][dc] = val;
  }
  __syncthreads();
#pragma unroll
  for (int i = 0; i < 2; ++i) {
    const int c = i * 256 + tid;
    const int d = c >> 3, kx = (c & 7) << 3;
    u16x8 o;
#pragma unroll
    for (int j = 0; j < 8; ++j) o[j] = ls[kx + j][d];
    *(u16x8*)(vt + ((size_t)n * 64 + d) * 448 + kc * 64 + kx) = o;
  }
}

// ---------------- fused attention, S^T formulation, 4 waves/block ----------------
#define PST 468  // P row stride (u16): dword stride 234 == 10 mod 32 -> ~2-way (free)
__global__ __launch_bounds__(256) void attn_kernel(
    const unsigned short* __restrict__ qt_, const unsigned short* __restrict__ kt_,
    const unsigned short* __restrict__ vt_, unsigned short* __restrict__ attn) {
  __shared__ __align__(16) unsigned short P[16 * PST];  // 14976 B
  __shared__ float Rm[4][16], Rs[4][16], Rc[4][16], Rv[4][16], R2[4][16];
  __shared__ __align__(16) float OT[4][16][17];         // per-wave transpose buffers
  const int id = blockIdx.x;
  const int xcd = id & 7, j0 = id >> 3;
  const int n = xcd * 32 + (j0 & 31), qt = j0 >> 5;  // qt 0..23
  const int b = n >> 4, h = n & 15;
  const int tid = threadIdx.x, w = tid >> 6, lane = tid & 63;
  const int lr = lane & 15, lq = lane >> 4;

  const unsigned short* qp = qt_ + ((size_t)n * 384 + qt * 16 + lr) * 64 + lq * 8;
  const bf16x8 q0 = *(const bf16x8*)qp;
  const bf16x8 q1 = *(const bf16x8*)(qp + 32);

  // phase 1: S^T for 7 k-tiles. acc[t][r] = S[q=lr][k = (w*7+t)*16 + 4*lq + r]
  f32x4 acc[7];
#pragma unroll
  for (int t = 0; t < 7; ++t) {
    const unsigned short* kp = kt_ + ((size_t)n * 448 + (w * 7 + t) * 16 + lr) * 64 + lq * 8;
    const bf16x8 k0 = *(const bf16x8*)kp;
    const bf16x8 k1 = *(const bf16x8*)(kp + 32);
    f32x4 a = {0.f, 0.f, 0.f, 0.f};
    a = __builtin_amdgcn_mfma_f32_16x16x32_bf16(k0, q0, a, 0, 0, 0);
    a = __builtin_amdgcn_mfma_f32_16x16x32_bf16(k1, q1, a, 0, 0, 0);
    acc[t] = a;
  }

  // ---- pass 1: row max ----
  f32x4 m4 = acc[0];
#pragma unroll
  for (int t = 1; t < 7; ++t) {
    m4[0] = fmaxf(m4[0], acc[t][0]); m4[1] = fmaxf(m4[1], acc[t][1]);
    m4[2] = fmaxf(m4[2], acc[t][2]); m4[3] = fmaxf(m4[3], acc[t][3]);
  }
  float m = fmaxf(fmaxf(m4[0], m4[1]), fmaxf(m4[2], m4[3]));
  m = fmaxf(m, __shfl_xor(m, 16));
  m = fmaxf(m, __shfl_xor(m, 32));
  if (lq == 0) Rm[w][lr] = m;
  __syncthreads();
  m = fmaxf(fmaxf(Rm[0][lr], Rm[1][lr]), fmaxf(Rm[2][lr], Rm[3][lr]));

  // ---- exp in place; pass 2: sum + nonzero count ----
  f32x4 s4 = {0.f, 0.f, 0.f, 0.f}, c4 = {0.f, 0.f, 0.f, 0.f};
#pragma unroll
  for (int t = 0; t < 7; ++t) {
#pragma unroll
    for (int r = 0; r < 4; ++r) {
      const float e = __expf(acc[t][r] - m);
      acc[t][r] = e;
      s4[r] += e;
      if (e > 0.f) c4[r] += 1.f;
    }
  }
  float s = (s4[0] + s4[1]) + (s4[2] + s4[3]);
  float cnt = (c4[0] + c4[1]) + (c4[2] + c4[3]);
  s += __shfl_xor(s, 16); s += __shfl_xor(s, 32);
  cnt += __shfl_xor(cnt, 16); cnt += __shfl_xor(cnt, 32);
  if (lq == 0) { Rs[w][lr] = s; Rc[w][lr] = cnt; }
  __syncthreads();
  s = (Rs[0][lr] + Rs[1][lr]) + (Rs[2][lr] + Rs[3][lr]);
  cnt = (Rc[0][lr] + Rc[1][lr]) + (Rc[2][lr] + Rc[3][lr]);
  const float inv = 1.f / s;
  const float mean = 1.f / cnt;  // sum(p) == 1

  // ---- pass 3: variance of p over nonzeros ----
  f32x4 d4 = {0.f, 0.f, 0.f, 0.f};
#pragma unroll
  for (int t = 0; t < 7; ++t) {
#pragma unroll
    for (int r = 0; r < 4; ++r) {
      const float p = acc[t][r] * inv;
      const float dd = p - mean;
      if (acc[t][r] > 0.f) d4[r] += dd * dd;
    }
  }
  float dv = (d4[0] + d4[1]) + (d4[2] + d4[3]);
  dv += __shfl_xor(dv, 16); dv += __shfl_xor(dv, 32);
  if (lq == 0) Rv[w][lr] = dv;
  __syncthreads();
  dv = (Rv[0][lr] + Rv[1][lr]) + (Rv[2][lr] + Rv[3][lr]);
  const float thr = mean - 0.5f * sqrtf(dv / (cnt - 1.f));

  // ---- pass 4: survivor renormalizer (row max always survives: p_max >= mean >= thr) ----
  f32x4 t4 = {0.f, 0.f, 0.f, 0.f};
#pragma unroll
  for (int t = 0; t < 7; ++t) {
#pragma unroll
    for (int r = 0; r < 4; ++r) {
      if (!(acc[t][r] * inv < thr)) t4[r] += acc[t][r];
    }
  }
  float s2 = (t4[0] + t4[1]) + (t4[2] + t4[3]);
  s2 += __shfl_xor(s2, 16); s2 += __shfl_xor(s2, 32);
  if (lq == 0) R2[w][lr] = s2;
  __syncthreads();
  s2 = (R2[0][lr] + R2[1][lr]) + (R2[2][lr] + R2[3][lr]);
  const float inv2 = 1.f / s2;

  // ---- write P[q=lr][k] bf16 (wave w covers k in [w*112, w*112+112)) ----
#pragma unroll
  for (int t = 0; t < 7; ++t) {
#pragma unroll
    for (int rp = 0; rp < 4; rp += 2) {
      const float v0 = (acc[t][rp] * inv < thr) ? 0.f : acc[t][rp] * inv2;
      const float v1 = (acc[t][rp + 1] * inv < thr) ? 0.f : acc[t][rp + 1] * inv2;
      const unsigned int u = (unsigned int)f2bf(v0) | ((unsigned int)f2bf(v1) << 16);
      *(unsigned int*)&P[lr * PST + (w * 7 + t) * 16 + lq * 4 + rp] = u;
    }
  }
  __syncthreads();

  // phase 3: out^T[d][q] = V^T(64x448) . P(448x16). Wave w owns d-tile [w*16, w*16+16).
  f32x4 o = {0.f, 0.f, 0.f, 0.f};
#pragma unroll
  for (int c = 0; c < 14; ++c) {
    union { ushort4 hh[2]; bf16x8 v; } bf;
    bf.hh[0] = *(const ushort4*)&P[lr * PST + c * 32 + lq * 8];
    bf.hh[1] = *(const ushort4*)&P[lr * PST + c * 32 + lq * 8 + 4];
    const bf16x8 a = *(const bf16x8*)(vt_ + ((size_t)n * 64 + w * 16 + lr) * 448 + c * 32 + lq * 8);
    o = __builtin_amdgcn_mfma_f32_16x16x32_bf16(a, bf.v, o, 0, 0, 0);
  }

  // transpose 16x16 tile via wave-private LDS (no barrier: same-wave write->read)
#pragma unroll
  for (int r = 0; r < 4; ++r) OT[w][lq * 4 + r][lr] = o[r];
  const int qrow = lane >> 2, dg = lane & 3;
  ushort4 ov;
  ov.x = f2bf(OT[w][dg * 4 + 0][qrow]);
  ov.y = f2bf(OT[w][dg * 4 + 1][qrow]);
  ov.z = f2bf(OT[w][dg * 4 + 2][qrow]);
  ov.w = f2bf(OT[w][dg * 4 + 3][qrow]);
  *(ushort4*)(attn + ((size_t)(qt * 16 + qrow) * 16 + b) * 1024 + h * 64 + w * 16 + dg * 4) = ov;
}

// ---------------- launch ----------------
extern "C" void kernel_launch(void* const* d_in, const int* in_sizes, int n_in,
                              void* d_out, int out_size, void* d_ws, size_t ws_size,
                              hipStream_t stream) {
  (void)in_sizes; (void)n_in; (void)out_size; (void)ws_size;
  const float* x    = (const float*)d_in[0];
  const float* mem  = (const float*)d_in[1];
  const float* q_w  = (const float*)d_in[2];
  const float* q_b  = (const float*)d_in[3];
  const float* k_w  = (const float*)d_in[4];
  const float* k_b  = (const float*)d_in[5];
  const float* v_w  = (const float*)d_in[6];
  const float* v_b  = (const float*)d_in[7];
  const float* o_w  = (const float*)d_in[8];
  const float* o_b  = (const float*)d_in[9];
  const float* ln1w = (const float*)d_in[10];
  const float* ln1b = (const float*)d_in[11];
  const float* f1w  = (const float*)d_in[12];
  const float* f1b  = (const float*)d_in[13];
  const float* f2w  = (const float*)d_in[14];
  const float* f2b  = (const float*)d_in[15];
  const float* ln2w = (const float*)d_in[16];
  const float* ln2b = (const float*)d_in[17];

  unsigned short* WQ   = (unsigned short*)d_ws;        // 3x 1048576 contiguous = fused B
  unsigned short* WK   = WQ + 1048576;
  unsigned short* WV   = WK + 1048576;
  unsigned short* WO   = WV + 1048576;
  unsigned short* WF1  = WO + 1048576;                 // 4194304
  unsigned short* WF2  = WF1 + 4194304;                // 4194304
  unsigned short* ABUF = WF2 + 4194304;                // 7340032 (mem rows 0..1023, xn rows 1024..7167)
  unsigned short* QB   = ABUF + 7340032;               // 6291456 [n][384][64]; KB/VB at KOFF/VOFF
  unsigned short* KB   = QB + 6291456;                 // 7340032 [n][448][64]
  unsigned short* VB   = KB + 7340032;                 // 7340032 [n][448][64]
  unsigned short* VT   = VB + 7340032;                 // 7340032 [n][64][448]
  unsigned short* ATTN = VT + 7340032;                 // 6291456
  float*          X2   = (float*)(ATTN + 6291456);     // 6291456 f32
  float*          QKVB = (float*)ATTN;                 // 3072 f32, dead before attn writes ATTN
  unsigned short* XN2  = ATTN;                         // alias (attn dead after out-proj)
  unsigned short* HB   = ABUF;                         // alias (A/q/k/v staging dead after attention)

  // all weight/memory converts + bias concat in ONE launch
  cvt_all<<<13324, 256, 0, stream>>>(q_w, k_w, v_w, o_w, f1w, f2w, mem, q_b, k_b, v_b,
                                     WQ, WK, WV, WO, WF1, WF2, ABUF, QKVB);

  // LN1 -> xn (rows 1024.. of ABUF)
  ln_bf16<0><<<6144, 256, 0, stream>>>(x, ABUF + 1048576, ln1w, ln1b, nullptr, nullptr);

  // fused QKV: [mem;xn] x [Wq;Wk;Wv]^T, head-major epilogue. NBM=56 -> WM=7, NBN=24.
  gemm_bt<5><<<1344, 256, 0, stream>>>(ABUF, WQ, QKVB, nullptr, QB, 7168, 3072, 1024, 1024, 1024, 24, 7);

  vtrans<<<dim3(7, 256), 256, 0, stream>>>(VB, VT);
  attn_kernel<<<6144, 256, 0, stream>>>(QB, KB, VT, ATTN);

  // out-proj + residual -> X2 (f32). NBM=48 -> WM=6, NBN=8.
  gemm_bt<2><<<384, 256, 0, stream>>>(ATTN, WO, o_b, x, X2, 6144, 1024, 1024, 1024, 1024, 8, 6);

  // LN2 -> xn2, and prefill d_out = X2 + fc2_bias (for split-K atomic fc2)
  ln_bf16<1><<<6144, 256, 0, stream>>>(X2, XN2, ln2w, ln2b, f2b, (float*)d_out);

  // FFN. fc1: 2-phase/kt 256x128 engine. grid 768 = 8 XCD x (3 m-tiles x 32 n-tiles)
  //           = exactly 3 blocks/CU rounds (no tail waste).
  gemm8_relu<<<768, 512, 0, stream>>>(XN2, WF1, f1b, HB, 4096, 1024, 1024, 3);
  // fc2: m97-style, WM=6, NBN=8, split-K=2 (z = rest/NBN).
  gemm_bt<6><<<768, 256, 0, stream>>>(HB, WF2, nullptr, nullptr, d_out, 6144, 1024, 2048, 4096, 4096, 8, 6);
}

// Round 3
// 517.706 us; speedup vs baseline: 3.1808x; 3.1808x over previous
//
#include <hip/hip_runtime.h>

// ---------------- types / helpers ----------------
typedef __bf16 bf16x8 __attribute__((ext_vector_type(8)));
typedef float f32x4 __attribute__((ext_vector_type(4)));
typedef unsigned short u16x8 __attribute__((ext_vector_type(8)));

__device__ __forceinline__ unsigned short f2bf(float f) {
  union { float f; unsigned int u; } v; v.f = f;
  unsigned int r = v.u + 0x7fffu + ((v.u >> 16) & 1u);  // RNE
  return (unsigned short)(r >> 16);
}

__device__ __forceinline__ void async16(const unsigned short* g, unsigned short* l) {
  __builtin_amdgcn_global_load_lds(
      (const __attribute__((address_space(1))) unsigned int*)g,
      (__attribute__((address_space(3))) unsigned int*)l, 16, 0, 0);
}

// ---------------- fused converts: all weights + memory + bias concat, ONE launch ------
__global__ void cvt_all(const float* __restrict__ q_w, const float* __restrict__ k_w,
                        const float* __restrict__ v_w, const float* __restrict__ o_w,
                        const float* __restrict__ f1w, const float* __restrict__ f2w,
                        const float* __restrict__ mem,
                        const float* __restrict__ q_b, const float* __restrict__ k_b,
                        const float* __restrict__ v_b,
                        unsigned short* __restrict__ WQ, unsigned short* __restrict__ WK,
                        unsigned short* __restrict__ WV, unsigned short* __restrict__ WO,
                        unsigned short* __restrict__ WF1, unsigned short* __restrict__ WF2,
                        unsigned short* __restrict__ MEMB, float* __restrict__ QKVB) {
  const int bid = blockIdx.x;
  const float* src; unsigned short* dst; float scale = 1.f; int base;
  if (bid < 1024)       { src = q_w; dst = WQ;  scale = 0.125f; base = 0; }
  else if (bid < 2048)  { src = k_w; dst = WK;  base = 1024; }
  else if (bid < 3072)  { src = v_w; dst = WV;  base = 2048; }
  else if (bid < 4096)  { src = o_w; dst = WO;  base = 3072; }
  else if (bid < 8192)  { src = f1w; dst = WF1; base = 4096; }
  else if (bid < 12288) { src = f2w; dst = WF2; base = 8192; }
  else if (bid < 13312) { src = mem; dst = MEMB; base = 12288; }
  else {  // bias concat (12 blocks, 3072 elems), q-bias pre-scaled
    const int i = (bid - 13312) * 256 + threadIdx.x;
    QKVB[i] = (i < 1024) ? q_b[i] * 0.125f : (i < 2048 ? k_b[i - 1024] : v_b[i - 2048]);
    return;
  }
  const int i = (bid - base) * 256 + threadIdx.x;
  float4 v = ((const float4*)src)[i];
  ushort4 o;
  o.x = f2bf(v.x * scale); o.y = f2bf(v.y * scale);
  o.z = f2bf(v.z * scale); o.w = f2bf(v.w * scale);
  ((ushort4*)dst)[i] = o;
}

// ---------------- LayerNorm (per 1024-row) -> bf16 ----------------
template <int PREFILL>
__global__ __launch_bounds__(256) void ln_bf16(
    const float* __restrict__ src, unsigned short* __restrict__ dst,
    const float* __restrict__ g, const float* __restrict__ be,
    const float* __restrict__ fbias, float* __restrict__ dout) {
  const int row = blockIdx.x, tid = threadIdx.x;
  const float4 v = ((const float4*)(src + (size_t)row * 1024))[tid];
  if (PREFILL) {
    const float4 fb = ((const float4*)fbias)[tid];
    float4 r;
    r.x = v.x + fb.x; r.y = v.y + fb.y; r.z = v.z + fb.z; r.w = v.w + fb.w;
    ((float4*)(dout + (size_t)row * 1024))[tid] = r;
  }
  float s = v.x + v.y + v.z + v.w;
  float qq = v.x * v.x + v.y * v.y + v.z * v.z + v.w * v.w;
#pragma unroll
  for (int off = 32; off; off >>= 1) { s += __shfl_xor(s, off); qq += __shfl_xor(qq, off); }
  __shared__ float ps[4], pq[4];
  const int w = tid >> 6, lane = tid & 63;
  if (lane == 0) { ps[w] = s; pq[w] = qq; }
  __syncthreads();
  if (tid == 0) { ps[0] = ps[0] + ps[1] + ps[2] + ps[3]; pq[0] = pq[0] + pq[1] + pq[2] + pq[3]; }
  __syncthreads();
  const float mu = ps[0] * (1.f / 1024.f);
  const float var = pq[0] * (1.f / 1024.f) - mu * mu;
  const float rs = rsqrtf(var + 1e-5f);
  const float4 gv = ((const float4*)g)[tid];
  const float4 bv = ((const float4*)be)[tid];
  ushort4 o;
  o.x = f2bf((v.x - mu) * rs * gv.x + bv.x);
  o.y = f2bf((v.y - mu) * rs * gv.y + bv.y);
  o.z = f2bf((v.z - mu) * rs * gv.z + bv.z);
  o.w = f2bf((v.w - mu) * rs * gv.w + bv.w);
  ((ushort4*)(dst + (size_t)row * 1024))[tid] = o;
}

// ---------------- GEMM: C[M,N] = A[M,K] @ B[N,K]^T (+ bias), m97-style ----------------
// __launch_bounds__(256, 4): cap regs at 128 (insurance vs co-compile perturbation,
// rule #19) WITHOUT forcing a spill. Round-2's (256,8) forced VGPR=32 -> accumulator
// spill to scratch (FETCH 57MB->906MB, MfmaUtil 3%, 615us/dispatch). Natural alloc
// is ~80 regs; occupancy here is grid/block-limited (~12 waves/CU), not VGPR-limited.
#define KOFF 6291456ull
#define VOFF 13631488ull
template <int EPI>
__global__ __launch_bounds__(256, 4) void gemm_bt(
    const unsigned short* __restrict__ A, const unsigned short* __restrict__ Bw,
    const float* __restrict__ bias, const float* __restrict__ resid,
    void* __restrict__ Cout, int M, int N, int K, int lda, int ldb, int NBN, int WM) {
  __shared__ __align__(16) unsigned short lA[128 * 32];
  __shared__ __align__(16) unsigned short lB[128 * 32];
  const int tid = threadIdx.x;
  const int w = tid >> 6, lane = tid & 63;
  const int lr = lane & 15, lq = lane >> 4;
  const int l = blockIdx.x;
  const int xcd = l & 7, r = l >> 3;
  const int bm = xcd * WM + (r % WM);
  const int rest = r / WM;
  const int bn = rest % NBN;
  const size_t koff = (size_t)(rest / NBN) * K;  // split-K offset
  const unsigned short* Ab = A + (size_t)bm * 128 * lda + koff;
  const unsigned short* Bb = Bw + (size_t)bn * 128 * ldb + koff;
  const int wm = (w & 1) << 6, wn = (w >> 1) << 6;
  f32x4 acc[4][4] = {};
  const int kiters = K >> 5;
  const int c0 = tid, c1 = 256 + tid;
  const int r0 = c0 >> 2, o0 = (c0 & 3) << 3;
  const int r1 = c1 >> 2, o1 = (c1 & 3) << 3;
  for (int kt = 0; kt < kiters; ++kt) {
    const int kb = kt << 5;
    __syncthreads();
    async16(Ab + (size_t)r0 * lda + kb + o0, lA + c0 * 8);
    async16(Bb + (size_t)r0 * ldb + kb + o0, lB + c0 * 8);
    async16(Ab + (size_t)r1 * lda + kb + o1, lA + c1 * 8);
    async16(Bb + (size_t)r1 * ldb + kb + o1, lB + c1 * 8);
    __syncthreads();
    bf16x8 af[4], bfr[4];
#pragma unroll
    for (int i = 0; i < 4; ++i) af[i] = *(const bf16x8*)(lA + (wm + i * 16 + lr) * 32 + lq * 8);
#pragma unroll
    for (int i = 0; i < 4; ++i) bfr[i] = *(const bf16x8*)(lB + (wn + i * 16 + lr) * 32 + lq * 8);
#pragma unroll
    for (int i = 0; i < 4; ++i)
#pragma unroll
      for (int j = 0; j < 4; ++j)
        acc[i][j] = __builtin_amdgcn_mfma_f32_16x16x32_bf16(af[i], bfr[j], acc[i][j], 0, 0, 0);
  }
  const int which = (bn * 128) >> 10;  // EPI5: 0=Q,1=K,2=V (block-uniform; 1024%128==0)
#pragma unroll
  for (int i = 0; i < 4; ++i) {
#pragma unroll
    for (int j = 0; j < 4; ++j) {
      const int colg = bn * 128 + wn + j * 16 + lr;
      const float bi = (EPI == 6) ? 0.f : bias[colg];
      const int rowg0 = bm * 128 + wm + i * 16 + lq * 4;
#pragma unroll
      for (int r2 = 0; r2 < 4; ++r2) {
        const int rowg = rowg0 + r2;
        const float val = acc[i][j][r2] + bi;
        if (EPI == 5) {
          const int t = rowg >> 4, bb = rowg & 15;
          const int hh = (colg >> 6) & 15, dd = colg & 63;
          const size_t nn = (size_t)(bb * 16 + hh);
          unsigned short* q16 = (unsigned short*)Cout;
          if (which == 0) {
            if (rowg >= 1024) q16[(nn * 384 + (t - 64)) * 64 + dd] = f2bf(val);
          } else if (which == 1) {
            q16[KOFF + (nn * 448 + t) * 64 + dd] = f2bf(val);
          } else {
            q16[VOFF + (nn * 448 + t) * 64 + dd] = f2bf(val);
          }
        } else {
          const size_t idx = (size_t)rowg * N + colg;
          if (EPI == 2) ((float*)Cout)[idx] = val + resid[idx];
          else if (EPI == 3) ((unsigned short*)Cout)[idx] = f2bf(fmaxf(val, 0.f));
          else if (EPI == 6) atomicAdd(&((float*)Cout)[idx], acc[i][j][r2]);
        }
      }
    }
  }
}

// ---------------- 2-phase/kt 256x128 GEMM engine (counted vmcnt + setprio) ----------
// C = relu(A[M,K]@B[N,K]^T + bias) -> bf16. K=1024 fixed (16 k-tiles of BK=64).
// BM=256, BN=128 -> fc1 grid = 24*32 = 768 = exactly 3 full rounds on 256 CUs.
// 512 thr = 8 waves (4M x 2N), per-wave 64x64 output (acc 4x4 f32x4 = 64 regs).
// LDS 96 KiB: A [2 buf][2 ks][256][32], B [2 buf][2 ks][128][32].
// Phase (2 per kt): head {lgkmcnt(0); vmcnt(6) counted; s_barrier} ; stage one
// (A-ks,B-ks) pair of kt+2 (3 loads/thread); ds_read next phase's frags; setprio(1);
// 16 MFMA; setprio(0). In-flight ledger: 3 loads/phase, 2 kt ahead -> at every
// steady head the oldest-6 drain is exactly the region read this phase. Tail
// (kt>=14) drains vmcnt 0 so nothing is in flight at endpgm.
// NOTE: this schedule passed the harness refcheck in round 2 (absmax unchanged).
#define WAITV6()  asm volatile("s_waitcnt vmcnt(6)" ::: "memory")
#define WAITV0()  asm volatile("s_waitcnt vmcnt(0)" ::: "memory")
#define WAITL0()  asm volatile("s_waitcnt lgkmcnt(0)" ::: "memory")
#define BAR()     do { __builtin_amdgcn_s_barrier(); __builtin_amdgcn_sched_barrier(0); } while (0)
#define SCHED()   __builtin_amdgcn_sched_barrier(0)

#define STG_A(bufv, ksv, ktv) do { \
    unsigned short* d_ = (unsigned short*)lA8 + (bufv) * 16384 + (ksv) * 8192; \
    const unsigned short* s_ = Ab + (((ktv) << 6) + ((ksv) << 5)); \
    async16(s_ + (size_t)ar0 * lda + ac0, d_ + ci0 * 8); \
    async16(s_ + (size_t)ar1 * lda + ac1, d_ + ci1 * 8); } while (0)
#define STG_B(bufv, ksv, ktv) do { \
    unsigned short* d_ = (unsigned short*)lB8 + (bufv) * 8192 + (ksv) * 4096; \
    const unsigned short* s_ = Bb + (((ktv) << 6) + ((ksv) << 5)); \
    async16(s_ + (size_t)br0 * ldb + bc0, d_ + tid * 8); } while (0)
#define RD_A4(dst, bufv, ksv) \
  _Pragma("unroll") \
  for (int i = 0; i < 4; ++i) \
    dst[i] = *(const bf16x8*)((unsigned short*)lA8 + (bufv) * 16384 + (ksv) * 8192 + \
                              (wm * 64 + i * 16 + lr) * 32 + lq * 8)
#define RD_B4(dst, bufv, ksv) \
  _Pragma("unroll") \
  for (int j = 0; j < 4; ++j) \
    dst[j] = *(const bf16x8*)((unsigned short*)lB8 + (bufv) * 8192 + (ksv) * 4096 + \
                              (wn * 64 + j * 16 + lr) * 32 + lq * 8)
#define MFMA16(av, bv) \
  _Pragma("unroll") \
  for (int i = 0; i < 4; ++i) \
  _Pragma("unroll") \
  for (int j = 0; j < 4; ++j) \
    acc[i][j] = \
        __builtin_amdgcn_mfma_f32_16x16x32_bf16(av[i], bv[j], acc[i][j], 0, 0, 0)

__global__ __launch_bounds__(512, 1) void gemm8_relu(
    const unsigned short* __restrict__ A, const unsigned short* __restrict__ Bw,
    const float* __restrict__ bias, unsigned short* __restrict__ Cout,
    int N, int lda, int ldb, int MT) {  // grid must be 8 * MT * (N/128)
  __shared__ __align__(16) unsigned short lA8[32768];  // [2][2][256][32] u16 = 64 KiB
  __shared__ __align__(16) unsigned short lB8[16384];  // [2][2][128][32] u16 = 32 KiB
  const int tid = threadIdx.x;
  const int w = tid >> 6, lane = tid & 63;
  const int wm = w >> 1, wn = w & 1;          // wave grid 4 (M) x 2 (N)
  const int lr = lane & 15, lq = lane >> 4;
  const int bid = blockIdx.x;
  const int xcd = bid & 7, r = bid >> 3;
  const int bm = xcd * MT + (r % MT);         // per-XCD contiguous A stripe (L2 reuse)
  const int bn = r / MT;
  const unsigned short* Ab = A + (size_t)bm * 256 * lda;
  const unsigned short* Bb = Bw + (size_t)bn * 128 * ldb;
  // staging: A region = 16KB = 1024 chunks (thread owns tid, tid+512);
  //          B region =  8KB =  512 chunks (thread owns tid). LDS dest linear in chunk.
  const int ci0 = tid, ci1 = tid + 512;
  const int ar0 = ci0 >> 2, ac0 = (ci0 & 3) << 3;
  const int ar1 = ci1 >> 2, ac1 = (ci1 & 3) << 3;
  const int br0 = tid >> 2, bc0 = (tid & 3) << 3;

  f32x4 acc[4][4] = {};
  bf16x8 aP[4], aN[4], b0[4], b1[4];

  // prologue: stage kt0 -> buf0, kt1 -> buf1 (6 loads each)
  STG_B(0, 0, 0); STG_A(0, 0, 0); STG_B(0, 1, 0); STG_A(0, 1, 0);
  STG_B(1, 0, 1); STG_A(1, 0, 1); STG_B(1, 1, 1); STG_A(1, 1, 1);
  WAITV6();   // kt0's 6 landed; kt1's 6 stay in flight
  BAR();
  RD_A4(aP, 0, 0);
  RD_B4(b0, 0, 0);

  for (int kt = 0; kt < 16; ++kt) {
    const int buf = kt & 1, nbuf = buf ^ 1, kt2 = kt + 2;
    const bool st = kt2 < 16, tail = kt >= 14;
    // ---- phase 0: MFMA ks0 ; stage (B,A)-ks0 of kt+2 ; read ks1 frags of kt
    WAITL0(); if (tail) { WAITV0(); } else { WAITV6(); } BAR();
    if (st) { STG_B(buf, 0, kt2); STG_A(buf, 0, kt2); }
    RD_A4(aN, buf, 1);
    RD_B4(b1, buf, 1);
    SCHED();
    __builtin_amdgcn_s_setprio(1);
    MFMA16(aP, b0);
    __builtin_amdgcn_s_setprio(0);
    // ---- phase 1: MFMA ks1 ; stage (B,A)-ks1 of kt+2 ; read ks0 frags of kt+1
    WAITL0(); if (tail) { WAITV0(); } else { WAITV6(); } BAR();
    if (st) { STG_B(buf, 1, kt2); STG_A(buf, 1, kt2); }
    if (kt < 15) { RD_A4(aP, nbuf, 0); RD_B4(b0, nbuf, 0); }
    SCHED();
    __builtin_amdgcn_s_setprio(1);
    MFMA16(aN, b1);
    __builtin_amdgcn_s_setprio(0);
  }

  // epilogue: relu(acc + bias) -> bf16 (same lane->(row,col) mapping as gemm_bt, proven)
#pragma unroll
  for (int j = 0; j < 4; ++j) {
    const int colg = bn * 128 + wn * 64 + j * 16 + lr;
    const float bi = bias[colg];
#pragma unroll
    for (int i = 0; i < 4; ++i) {
      const int rowg0 = bm * 256 + wm * 64 + i * 16 + lq * 4;
#pragma unroll
      for (int r2 = 0; r2 < 4; ++r2) {
        const float v = acc[i][j][r2] + bi;
        Cout[(size_t)(rowg0 + r2) * N + colg] = f2bf(fmaxf(v, 0.f));
      }
    }
  }
}

// ---------------- V transpose: vb[n][t][d] -> vt[n][d][t] ----------------
__global__ __launch_bounds__(256) void vtrans(const unsigned short* __restrict__ vb,
                                              unsigned short* __restrict__ vt) {
  __shared__ __align__(16) unsigned short ls[64][80];
  const int kc = blockIdx.x, n = blockIdx.y;
  const int tid = threadIdx.x;
#pragma unroll
  for (int i = 0; i < 2; ++i) {
    const int c = i * 256 + tid;
    const int kk = c >> 3, dc = (c & 7) << 3;
    u16x8 val = *(const u16x8*)(vb + ((size_t)n * 448 + kc * 64 + kk) * 64 + dc);
    *(u16x8*)&ls[kk][dc] = val;
  }
  __syncthreads();
#pragma unroll
  for (int i = 0; i < 2; ++i) {
    const int c = i * 256 + tid;
    const int d = c >> 3, kx = (c & 7) << 3;
    u16x8 o;
#pragma unroll
    for (int j = 0; j < 8; ++j) o[j] = ls[kx + j][d];
    *(u16x8*)(vt + ((size_t)n * 64 + d) * 448 + kc * 64 + kx) = o;
  }
}

// ---------------- fused attention, S^T formulation, 4 waves/block ----------------
#define PST 468  // P row stride (u16): dword stride 234 == 10 mod 32 -> ~2-way (free)
__global__ __launch_bounds__(256) void attn_kernel(
    const unsigned short* __restrict__ qt_, const unsigned short* __restrict__ kt_,
    const unsigned short* __restrict__ vt_, unsigned short* __restrict__ attn) {
  __shared__ __align__(16) unsigned short P[16 * PST];  // 14976 B
  __shared__ float Rm[4][16], Rs[4][16], Rc[4][16], Rv[4][16], R2[4][16];
  __shared__ __align__(16) float OT[4][16][17];         // per-wave transpose buffers
  const int id = blockIdx.x;
  const int xcd = id & 7, j0 = id >> 3;
  const int n = xcd * 32 + (j0 & 31), qt = j0 >> 5;  // qt 0..23
  const int b = n >> 4, h = n & 15;
  const int tid = threadIdx.x, w = tid >> 6, lane = tid & 63;
  const int lr = lane & 15, lq = lane >> 4;

  const unsigned short* qp = qt_ + ((size_t)n * 384 + qt * 16 + lr) * 64 + lq * 8;
  const bf16x8 q0 = *(const bf16x8*)qp;
  const bf16x8 q1 = *(const bf16x8*)(qp + 32);

  // phase 1: S^T for 7 k-tiles. acc[t][r] = S[q=lr][k = (w*7+t)*16 + 4*lq + r]
  f32x4 acc[7];
#pragma unroll
  for (int t = 0; t < 7; ++t) {
    const unsigned short* kp = kt_ + ((size_t)n * 448 + (w * 7 + t) * 16 + lr) * 64 + lq * 8;
    const bf16x8 k0 = *(const bf16x8*)kp;
    const bf16x8 k1 = *(const bf16x8*)(kp + 32);
    f32x4 a = {0.f, 0.f, 0.f, 0.f};
    a = __builtin_amdgcn_mfma_f32_16x16x32_bf16(k0, q0, a, 0, 0, 0);
    a = __builtin_amdgcn_mfma_f32_16x16x32_bf16(k1, q1, a, 0, 0, 0);
    acc[t] = a;
  }

  // ---- pass 1: row max ----
  f32x4 m4 = acc[0];
#pragma unroll
  for (int t = 1; t < 7; ++t) {
    m4[0] = fmaxf(m4[0], acc[t][0]); m4[1] = fmaxf(m4[1], acc[t][1]);
    m4[2] = fmaxf(m4[2], acc[t][2]); m4[3] = fmaxf(m4[3], acc[t][3]);
  }
  float m = fmaxf(fmaxf(m4[0], m4[1]), fmaxf(m4[2], m4[3]));
  m = fmaxf(m, __shfl_xor(m, 16));
  m = fmaxf(m, __shfl_xor(m, 32));
  if (lq == 0) Rm[w][lr] = m;
  __syncthreads();
  m = fmaxf(fmaxf(Rm[0][lr], Rm[1][lr]), fmaxf(Rm[2][lr], Rm[3][lr]));

  // ---- exp in place; pass 2: sum + nonzero count ----
  f32x4 s4 = {0.f, 0.f, 0.f, 0.f}, c4 = {0.f, 0.f, 0.f, 0.f};
#pragma unroll
  for (int t = 0; t < 7; ++t) {
#pragma unroll
    for (int r = 0; r < 4; ++r) {
      const float e = __expf(acc[t][r] - m);
      acc[t][r] = e;
      s4[r] += e;
      if (e > 0.f) c4[r] += 1.f;
    }
  }
  float s = (s4[0] + s4[1]) + (s4[2] + s4[3]);
  float cnt = (c4[0] + c4[1]) + (c4[2] + c4[3]);
  s += __shfl_xor(s, 16); s += __shfl_xor(s, 32);
  cnt += __shfl_xor(cnt, 16); cnt += __shfl_xor(cnt, 32);
  if (lq == 0) { Rs[w][lr] = s; Rc[w][lr] = cnt; }
  __syncthreads();
  s = (Rs[0][lr] + Rs[1][lr]) + (Rs[2][lr] + Rs[3][lr]);
  cnt = (Rc[0][lr] + Rc[1][lr]) + (Rc[2][lr] + Rc[3][lr]);
  const float inv = 1.f / s;
  const float mean = 1.f / cnt;  // sum(p) == 1

  // ---- pass 3: variance of p over nonzeros ----
  f32x4 d4 = {0.f, 0.f, 0.f, 0.f};
#pragma unroll
  for (int t = 0; t < 7; ++t) {
#pragma unroll
    for (int r = 0; r < 4; ++r) {
      const float p = acc[t][r] * inv;
      const float dd = p - mean;
      if (acc[t][r] > 0.f) d4[r] += dd * dd;
    }
  }
  float dv = (d4[0] + d4[1]) + (d4[2] + d4[3]);
  dv += __shfl_xor(dv, 16); dv += __shfl_xor(dv, 32);
  if (lq == 0) Rv[w][lr] = dv;
  __syncthreads();
  dv = (Rv[0][lr] + Rv[1][lr]) + (Rv[2][lr] + Rv[3][lr]);
  const float thr = mean - 0.5f * sqrtf(dv / (cnt - 1.f));

  // ---- pass 4: survivor renormalizer (row max always survives: p_max >= mean >= thr) ----
  f32x4 t4 = {0.f, 0.f, 0.f, 0.f};
#pragma unroll
  for (int t = 0; t < 7; ++t) {
#pragma unroll
    for (int r = 0; r < 4; ++r) {
      if (!(acc[t][r] * inv < thr)) t4[r] += acc[t][r];
    }
  }
  float s2 = (t4[0] + t4[1]) + (t4[2] + t4[3]);
  s2 += __shfl_xor(s2, 16); s2 += __shfl_xor(s2, 32);
  if (lq == 0) R2[w][lr] = s2;
  __syncthreads();
  s2 = (R2[0][lr] + R2[1][lr]) + (R2[2][lr] + R2[3][lr]);
  const float inv2 = 1.f / s2;

  // ---- write P[q=lr][k] bf16 (wave w covers k in [w*112, w*112+112)) ----
#pragma unroll
  for (int t = 0; t < 7; ++t) {
#pragma unroll
    for (int rp = 0; rp < 4; rp += 2) {
      const float v0 = (acc[t][rp] * inv < thr) ? 0.f : acc[t][rp] * inv2;
      const float v1 = (acc[t][rp + 1] * inv < thr) ? 0.f : acc[t][rp + 1] * inv2;
      const unsigned int u = (unsigned int)f2bf(v0) | ((unsigned int)f2bf(v1) << 16);
      *(unsigned int*)&P[lr * PST + (w * 7 + t) * 16 + lq * 4 + rp] = u;
    }
  }
  __syncthreads();

  // phase 3: out^T[d][q] = V^T(64x448) . P(448x16). Wave w owns d-tile [w*16, w*16+16).
  f32x4 o = {0.f, 0.f, 0.f, 0.f};
#pragma unroll
  for (int c = 0; c < 14; ++c) {
    union { ushort4 hh[2]; bf16x8 v; } bf;
    bf.hh[0] = *(const ushort4*)&P[lr * PST + c * 32 + lq * 8];
    bf.hh[1] = *(const ushort4*)&P[lr * PST + c * 32 + lq * 8 + 4];
    const bf16x8 a = *(const bf16x8*)(vt_ + ((size_t)n * 64 + w * 16 + lr) * 448 + c * 32 + lq * 8);
    o = __builtin_amdgcn_mfma_f32_16x16x32_bf16(a, bf.v, o, 0, 0, 0);
  }

  // transpose 16x16 tile via wave-private LDS (no barrier: same-wave write->read)
#pragma unroll
  for (int r = 0; r < 4; ++r) OT[w][lq * 4 + r][lr] = o[r];
  const int qrow = lane >> 2, dg = lane & 3;
  ushort4 ov;
  ov.x = f2bf(OT[w][dg * 4 + 0][qrow]);
  ov.y = f2bf(OT[w][dg * 4 + 1][qrow]);
  ov.z = f2bf(OT[w][dg * 4 + 2][qrow]);
  ov.w = f2bf(OT[w][dg * 4 + 3][qrow]);
  *(ushort4*)(attn + ((size_t)(qt * 16 + qrow) * 16 + b) * 1024 + h * 64 + w * 16 + dg * 4) = ov;
}

// ---------------- launch ----------------
extern "C" void kernel_launch(void* const* d_in, const int* in_sizes, int n_in,
                              void* d_out, int out_size, void* d_ws, size_t ws_size,
                              hipStream_t stream) {
  (void)in_sizes; (void)n_in; (void)out_size; (void)ws_size;
  const float* x    = (const float*)d_in[0];
  const float* mem  = (const float*)d_in[1];
  const float* q_w  = (const float*)d_in[2];
  const float* q_b  = (const float*)d_in[3];
  const float* k_w  = (const float*)d_in[4];
  const float* k_b  = (const float*)d_in[5];
  const float* v_w  = (const float*)d_in[6];
  const float* v_b  = (const float*)d_in[7];
  const float* o_w  = (const float*)d_in[8];
  const float* o_b  = (const float*)d_in[9];
  const float* ln1w = (const float*)d_in[10];
  const float* ln1b = (const float*)d_in[11];
  const float* f1w  = (const float*)d_in[12];
  const float* f1b  = (const float*)d_in[13];
  const float* f2w  = (const float*)d_in[14];
  const float* f2b  = (const float*)d_in[15];
  const float* ln2w = (const float*)d_in[16];
  const float* ln2b = (const float*)d_in[17];

  unsigned short* WQ   = (unsigned short*)d_ws;        // 3x 1048576 contiguous = fused B
  unsigned short* WK   = WQ + 1048576;
  unsigned short* WV   = WK + 1048576;
  unsigned short* WO   = WV + 1048576;
  unsigned short* WF1  = WO + 1048576;                 // 4194304
  unsigned short* WF2  = WF1 + 4194304;                // 4194304
  unsigned short* ABUF = WF2 + 4194304;                // 7340032 (mem rows 0..1023, xn rows 1024..7167)
  unsigned short* QB   = ABUF + 7340032;               // 6291456 [n][384][64]; KB/VB at KOFF/VOFF
  unsigned short* KB   = QB + 6291456;                 // 7340032 [n][448][64]
  unsigned short* VB   = KB + 7340032;                 // 7340032 [n][448][64]
  unsigned short* VT   = VB + 7340032;                 // 7340032 [n][64][448]
  unsigned short* ATTN = VT + 7340032;                 // 6291456
  float*          X2   = (float*)(ATTN + 6291456);     // 6291456 f32
  float*          QKVB = (float*)ATTN;                 // 3072 f32, dead before attn writes ATTN
  unsigned short* XN2  = ATTN;                         // alias (attn dead after out-proj)
  unsigned short* HB   = ABUF;                         // alias (A/q/k/v staging dead after attention)

  // all weight/memory converts + bias concat in ONE launch
  cvt_all<<<13324, 256, 0, stream>>>(q_w, k_w, v_w, o_w, f1w, f2w, mem, q_b, k_b, v_b,
                                     WQ, WK, WV, WO, WF1, WF2, ABUF, QKVB);

  // LN1 -> xn (rows 1024.. of ABUF)
  ln_bf16<0><<<6144, 256, 0, stream>>>(x, ABUF + 1048576, ln1w, ln1b, nullptr, nullptr);

  // fused QKV: [mem;xn] x [Wq;Wk;Wv]^T, head-major epilogue. NBM=56 -> WM=7, NBN=24.
  gemm_bt<5><<<1344, 256, 0, stream>>>(ABUF, WQ, QKVB, nullptr, QB, 7168, 3072, 1024, 1024, 1024, 24, 7);

  vtrans<<<dim3(7, 256), 256, 0, stream>>>(VB, VT);
  attn_kernel<<<6144, 256, 0, stream>>>(QB, KB, VT, ATTN);

  // out-proj + residual -> X2 (f32). NBM=48 -> WM=6, NBN=8.
  gemm_bt<2><<<384, 256, 0, stream>>>(ATTN, WO, o_b, x, X2, 6144, 1024, 1024, 1024, 1024, 8, 6);

  // LN2 -> xn2, and prefill d_out = X2 + fc2_bias (for split-K atomic fc2)
  ln_bf16<1><<<6144, 256, 0, stream>>>(X2, XN2, ln2w, ln2b, f2b, (float*)d_out);

  // FFN. fc1: 2-phase/kt 256x128 engine. grid 768 = 8 XCD x (3 m-tiles x 32 n-tiles)
  //           = exactly 3 full rounds (round-1's 384-block config wasted 25% in tail).
  gemm8_relu<<<768, 512, 0, stream>>>(XN2, WF1, f1b, HB, 4096, 1024, 1024, 3);
  // fc2: m97-style, WM=6, NBN=8, split-K=2 (z = rest/NBN).
  gemm_bt<6><<<768, 256, 0, stream>>>(HB, WF2, nullptr, nullptr, d_out, 6144, 1024, 2048, 4096, 4096, 8, 6);
}